// Round 1
// 537.525 us; speedup vs baseline: 1.1370x; 1.1370x over previous
//
#include <hip/hip_runtime.h>
#include <stdint.h>

// SparseLinear: out[m][n] = sum_k x[m][k] * W[n][k] * mask[n][k]
// M = B*S = 8192, N = 4096, K = 4096, fp32 in/out, bf16-tolerance check.
//
// R3: replace the 128^2 m97-structure GEMM (ceiling ~900 TF, MfmaUtil 37%)
// with the 256^2 / BK=64 / 8-phase counted-vmcnt template (T1+T2+T3+T4+T5):
//  - 512 threads = 8 waves (2 M x 4 N), per-wave 128x64 output, 16x16x32 MFMA
//  - LDS 128 KiB: per operand [2 dbuf][2 half(128 rows)][128][64] bf16
//  - staging granularity = half-tile (128x64), 2 global_load_lds(16B)/thread
//  - XOR chunk swizzle (chunk ^= row&7) via pre-swizzled global source +
//    swizzled ds_read addr (gload_lds dest must stay linear)
//  - 8 phases per 2 K-tiles; vmcnt(4) ONLY at phases 4 and 8 (never 0 in
//    the main loop): 6 half-tiles / 12 loads per thread stay in flight
//  - raw s_barrier (no compiler vmcnt(0) drain), lgkmcnt(0)+sched_barrier
//    before MFMA (rule 18), s_setprio(1) around MFMA clusters (T5)
// Schedule (race-free by barrier ordering; region overwrite always >= 1 full
// phase after that region's last ds_read):
//   P1: rdA(buf0 mi0-3)+rdB(buf0 ni0-1), stage T1.A0->buf1, Q(0,0)
//   P2: rdB(buf0 ni2-3),                 stage T1.A1->buf1, Q(0,2)
//   P3: rdA(buf0 mi4-7),                 stage T2.B0->buf0, Q(4,0)
//   P4:                                  stage T2.B1->buf0, Q(4,2), vmcnt(4)
//   P5: rdA(buf1 mi0-3)+rdB(buf1 ni0-1), stage T2.A0->buf0, Q(0,0)
//   P6: rdB(buf1 ni2-3),                 stage T2.A1->buf0, Q(0,2)
//   P7: rdA(buf1 mi4-7),                 stage T3.B0->buf1, Q(4,0)
//   P8:                                  stage T3.B1->buf1, Q(4,2), vmcnt(4)

static constexpr int Mdim = 8192;
static constexpr int Ndim = 4096;
static constexpr int Kdim = 4096;
static constexpr int BM = 256;
static constexpr int BN = 256;
static constexpr int BK = 64;
static constexpr int NT = Kdim / BK;  // 64 K-tiles

typedef __attribute__((ext_vector_type(8))) short short8;
typedef __attribute__((ext_vector_type(4))) float float4v;
typedef __attribute__((ext_vector_type(4))) float f32x4;
typedef __attribute__((ext_vector_type(4))) int int4v;
typedef __attribute__((ext_vector_type(8))) unsigned short ushort8;

__device__ __forceinline__ unsigned short f32_to_bf16(float f) {
  union { float f; uint32_t u; } c; c.f = f;
  uint32_t u = c.u;
  u += 0x7fffu + ((u >> 16) & 1u);   // round-to-nearest-even (no NaNs in data)
  return (unsigned short)(u >> 16);
}

// ---------------------------------------------------------------------------
// Mask element-width detection. numpy bool_ = 1 byte; int32/float32 promotion
// would zero byte positions ==1 (mod 4). 10% density over 1M positions ->
// ~105k hits for byte layout, exactly 0 for 4-byte layouts.
// ---------------------------------------------------------------------------
__global__ void detect_mask_kernel(const unsigned char* __restrict__ m, int* __restrict__ flag) {
  int found = 0;
  const int total = 1 << 20;  // scan first 4 MiB
  for (int p = blockIdx.x * blockDim.x + threadIdx.x; p < total;
       p += gridDim.x * blockDim.x)
    found |= (m[4 * p + 1] != 0);
  if (__any(found) && (threadIdx.x & 63) == 0) atomicOr(flag, 1);
}

// x fp32 -> bf16, 8 elements/thread (two 16B loads, one 16B store)
__global__ void cvt_x_kernel(const float* __restrict__ x, unsigned short* __restrict__ o) {
  long i = (blockIdx.x * (long)blockDim.x + threadIdx.x) * 8;
  float4v v0 = *(const float4v*)(x + i);
  float4v v1 = *(const float4v*)(x + i + 4);
  ushort8 r;
  r[0] = f32_to_bf16(v0[0]); r[1] = f32_to_bf16(v0[1]);
  r[2] = f32_to_bf16(v0[2]); r[3] = f32_to_bf16(v0[3]);
  r[4] = f32_to_bf16(v1[0]); r[5] = f32_to_bf16(v1[1]);
  r[6] = f32_to_bf16(v1[2]); r[7] = f32_to_bf16(v1[3]);
  *(ushort8*)(o + i) = r;
}

// W fp32 * mask -> bf16, 8 elements/thread; mask layout chosen by *flag
__global__ void cvt_w_kernel(const float* __restrict__ w, const unsigned char* __restrict__ mraw,
                             const int* __restrict__ flag, unsigned short* __restrict__ o) {
  long i = (blockIdx.x * (long)blockDim.x + threadIdx.x) * 8;
  float4v w0 = *(const float4v*)(w + i);
  float4v w1 = *(const float4v*)(w + i + 4);
  int m[8];
  if (*flag) {  // 1-byte elements
    unsigned long long mb = *(const unsigned long long*)(mraw + i);
#pragma unroll
    for (int j = 0; j < 8; ++j) m[j] = ((mb >> (8 * j)) & 0xffull) != 0;
  } else {      // 4-byte elements (int32 0/1 or float32 0.0/1.0 — both: nonzero word)
    int4v a = *(const int4v*)((const int*)mraw + i);
    int4v b = *(const int4v*)((const int*)mraw + i + 4);
#pragma unroll
    for (int j = 0; j < 4; ++j) { m[j] = a[j] != 0; m[4 + j] = b[j] != 0; }
  }
  ushort8 r;
  r[0] = f32_to_bf16(m[0] ? w0[0] : 0.0f);
  r[1] = f32_to_bf16(m[1] ? w0[1] : 0.0f);
  r[2] = f32_to_bf16(m[2] ? w0[2] : 0.0f);
  r[3] = f32_to_bf16(m[3] ? w0[3] : 0.0f);
  r[4] = f32_to_bf16(m[4] ? w1[0] : 0.0f);
  r[5] = f32_to_bf16(m[5] ? w1[1] : 0.0f);
  r[6] = f32_to_bf16(m[6] ? w1[2] : 0.0f);
  r[7] = f32_to_bf16(m[7] ? w1[3] : 0.0f);
  *(ushort8*)(o + i) = r;
}

// ---------------------------------------------------------------------------
// 8-phase 256x256 GEMM helpers
// ---------------------------------------------------------------------------

// Stage one 128x64 half-tile: per thread 2x global_load_lds(16B).
// LDS dest is linear; global source column is pre-swizzled: chunk ^= (row&7).
__device__ __forceinline__ void stage_half(const unsigned short* __restrict__ src,
                                           int grow_base, int kelem, char* region,
                                           int r0, int l0, int gcol) {
  const unsigned short* g0 = src + (size_t)(grow_base + r0) * Kdim + kelem + gcol;
  const unsigned short* g1 = src + (size_t)(grow_base + r0 + 8) * Kdim + kelem + gcol;
  __builtin_amdgcn_global_load_lds((const __attribute__((address_space(1))) void*)g0,
                                   (__attribute__((address_space(3))) void*)(region + l0),
                                   16, 0, 0);
  __builtin_amdgcn_global_load_lds((const __attribute__((address_space(1))) void*)g1,
                                   (__attribute__((address_space(3))) void*)(region + l0 + 1024),
                                   16, 0, 0);
}

// A fragment loads: rows mi*16 + (lane&15) of this wave's half, both K-halves.
// Read chunk = ((s<<2)|kg) ^ (row&7); row&7 == lane&7 for all our rows.
template <int BUF, int MI0>
__device__ __forceinline__ void load_a(short8 (&a)[4][2], const char* sA,
                                       int wm, int arow, int kg, int w7) {
#pragma unroll
  for (int mi = 0; mi < 4; ++mi) {
    const char* rowp = sA + (BUF * 2 + wm) * 16384 + ((MI0 + mi) * 16 + arow) * 128;
#pragma unroll
    for (int s = 0; s < 2; ++s)
      a[mi][s] = *(const short8*)(rowp + (((s << 2) | kg) ^ w7) * 16);
  }
}

template <int BUF, int NI0>
__device__ __forceinline__ void load_b(short8 (&b)[4][2], const char* sB,
                                       int wnh, int brow, int kg, int w7) {
#pragma unroll
  for (int ni = 0; ni < 2; ++ni) {
    const char* rowp = sB + (BUF * 2 + wnh) * 16384 + (brow + (NI0 + ni) * 16) * 128;
#pragma unroll
    for (int s = 0; s < 2; ++s)
      b[NI0 + ni][s] = *(const short8*)(rowp + (((s << 2) | kg) ^ w7) * 16);
  }
}

// One C-quadrant x K=64: 16 MFMA (4 mi x 2 ni x 2 k-halves)
template <int MIB, int NIB>
__device__ __forceinline__ void mfma_quad(f32x4 (&acc)[8][4], const short8 (&a)[4][2],
                                          const short8 (&b)[4][2]) {
#pragma unroll
  for (int s = 0; s < 2; ++s)
#pragma unroll
    for (int mi = 0; mi < 4; ++mi)
#pragma unroll
      for (int ni = 0; ni < 2; ++ni)
        acc[MIB + mi][NIB + ni] = __builtin_amdgcn_mfma_f32_16x16x32_bf16(
            a[mi][s], b[NIB + ni][s], acc[MIB + mi][NIB + ni], 0, 0, 0);
}

__device__ __forceinline__ void phase_pre() {
  __builtin_amdgcn_sched_barrier(0);
  __builtin_amdgcn_s_barrier();
  asm volatile("s_waitcnt lgkmcnt(0)" ::: "memory");
  __builtin_amdgcn_sched_barrier(0);
  __builtin_amdgcn_s_setprio(1);
}

__device__ __forceinline__ void phase_post() {
  __builtin_amdgcn_s_setprio(0);
  __builtin_amdgcn_sched_barrier(0);
  __builtin_amdgcn_s_barrier();
}

__device__ __forceinline__ void phase_post_vm() {
  __builtin_amdgcn_s_setprio(0);
  __builtin_amdgcn_sched_barrier(0);
  asm volatile("s_waitcnt vmcnt(4)" ::: "memory");  // counted: keep 2 stages in flight
  __builtin_amdgcn_sched_barrier(0);
  __builtin_amdgcn_s_barrier();
}

// ---------------------------------------------------------------------------
// bf16 MFMA GEMM, B^T form: O[m][n] = sum_k X[m][k]*W[n][k].
// A/B frag layout (16x16x32): m/n = lane&15, k = (lane>>4)*8 + i.
// C/D layout (m89-verified): col = lane&15, row = (lane>>4)*4 + reg.
// ---------------------------------------------------------------------------
__global__ __launch_bounds__(512, 2) void gemm_bt_kernel(const unsigned short* __restrict__ X,
                                                         const unsigned short* __restrict__ W,
                                                         float* __restrict__ O) {
  __shared__ __align__(16) char lds[131072];  // A: [0,64K), B: [64K,128K)
  char* sA = lds;
  char* sB = lds + 65536;

  const int tid = threadIdx.x;
  const int lane = tid & 63;
  const int wave = tid >> 6;
  const int wm = wave >> 2;        // 0..1 : M half (rows wm*128..+128)
  const int wn = wave & 3;         // 0..3 : N strip (cols wn*64..+64)
  const int wnh = wn >> 1;         // which B half this wave reads

  // T1: XCD-aware swizzle. 512 blocks, 8 XCDs -> 64 contiguous tiles per XCD.
  const int bid = blockIdx.x;
  const int id = (bid & 7) * 64 + (bid >> 3);
  const int tm = id >> 4;          // 0..31
  const int tn = id & 15;          // 0..15
  const int row0 = tm * BM;
  const int col0 = tn * BN;

  // staging per-thread constants
  const int r0 = wave * 16 + (lane >> 3);             // j=0 row within half
  const int gcol = ((lane & 7) ^ (lane >> 3)) * 8;    // pre-swizzled source col
  const int l0 = wave * 2048 + lane * 16;             // linear LDS byte offset

  // ds_read per-thread constants
  const int arow = lane & 15;
  const int kg = lane >> 4;        // 0..3
  const int w7 = lane & 7;         // == row&7 for every row we read
  const int brow = (wn & 1) * 64 + arow;

  f32x4 acc[8][4];
#pragma unroll
  for (int i = 0; i < 8; ++i)
#pragma unroll
    for (int j = 0; j < 4; ++j)
#pragma unroll
      for (int r = 0; r < 4; ++r) acc[i][j][r] = 0.f;

  short8 a[4][2], b[4][2];

  // Prologue: T0 complete (buf0) + T1.B halves (buf1) -> 12 loads/thread
  stage_half(X, row0 + 0,   0 * BK, sA + 0 * 16384, r0, l0, gcol);  // T0.A0
  stage_half(X, row0 + 128, 0 * BK, sA + 1 * 16384, r0, l0, gcol);  // T0.A1
  stage_half(W, col0 + 0,   0 * BK, sB + 0 * 16384, r0, l0, gcol);  // T0.B0
  stage_half(W, col0 + 128, 0 * BK, sB + 1 * 16384, r0, l0, gcol);  // T0.B1
  stage_half(W, col0 + 0,   1 * BK, sB + 2 * 16384, r0, l0, gcol);  // T1.B0
  stage_half(W, col0 + 128, 1 * BK, sB + 3 * 16384, r0, l0, gcol);  // T1.B1
  asm volatile("s_waitcnt vmcnt(4)" ::: "memory");  // T0 landed; T1.B in flight
  __builtin_amdgcn_sched_barrier(0);
  __builtin_amdgcn_s_barrier();

#pragma unroll 1
  for (int it = 0; it < NT / 2; ++it) {
    const int t1 = 2 * it + 1;
    const int t2 = (2 * it + 2) & (NT - 1);  // wrapped on last iter: staged, never read
    const int t3 = (2 * it + 3) & (NT - 1);

    // ================= tile 2*it from buf0 =================
    // P1
    load_a<0, 0>(a, sA, wm, arow, kg, w7);
    load_b<0, 0>(b, sB, wnh, brow, kg, w7);
    stage_half(X, row0 + 0, t1 * BK, sA + 2 * 16384, r0, l0, gcol);    // T1.A0
    phase_pre(); mfma_quad<0, 0>(acc, a, b); phase_post();
    // P2
    load_b<0, 2>(b, sB, wnh, brow, kg, w7);
    stage_half(X, row0 + 128, t1 * BK, sA + 3 * 16384, r0, l0, gcol);  // T1.A1
    phase_pre(); mfma_quad<0, 2>(acc, a, b); phase_post();
    // P3
    load_a<0, 4>(a, sA, wm, arow, kg, w7);
    stage_half(W, col0 + 0, t2 * BK, sB + 0 * 16384, r0, l0, gcol);    // T2.B0
    phase_pre(); mfma_quad<4, 0>(acc, a, b); phase_post();
    // P4
    stage_half(W, col0 + 128, t2 * BK, sB + 1 * 16384, r0, l0, gcol);  // T2.B1
    phase_pre(); mfma_quad<4, 2>(acc, a, b); phase_post_vm();          // T1 landed

    // ================= tile 2*it+1 from buf1 =================
    // P5
    load_a<1, 0>(a, sA, wm, arow, kg, w7);
    load_b<1, 0>(b, sB, wnh, brow, kg, w7);
    stage_half(X, row0 + 0, t2 * BK, sA + 0 * 16384, r0, l0, gcol);    // T2.A0
    phase_pre(); mfma_quad<0, 0>(acc, a, b); phase_post();
    // P6
    load_b<1, 2>(b, sB, wnh, brow, kg, w7);
    stage_half(X, row0 + 128, t2 * BK, sA + 1 * 16384, r0, l0, gcol);  // T2.A1
    phase_pre(); mfma_quad<0, 2>(acc, a, b); phase_post();
    // P7
    load_a<1, 4>(a, sA, wm, arow, kg, w7);
    stage_half(W, col0 + 0, t3 * BK, sB + 2 * 16384, r0, l0, gcol);    // T3.B0
    phase_pre(); mfma_quad<4, 0>(acc, a, b); phase_post();
    // P8
    stage_half(W, col0 + 128, t3 * BK, sB + 3 * 16384, r0, l0, gcol);  // T3.B1
    phase_pre(); mfma_quad<4, 2>(acc, a, b); phase_post_vm();          // T2 landed
  }

  // Epilogue: C/D row = (lane>>4)*4 + reg, col = lane&15
  const int orow0 = row0 + wm * 128 + kg * 4;
  const int ocol0 = col0 + wn * 64 + arow;
#pragma unroll
  for (int mi = 0; mi < 8; ++mi)
#pragma unroll
    for (int ni = 0; ni < 4; ++ni)
#pragma unroll
      for (int r = 0; r < 4; ++r)
        O[(size_t)(orow0 + mi * 16 + r) * Ndim + ocol0 + ni * 16] = acc[mi][ni][r];
}

// ---------------------------------------------------------------------------
// Fallback (only if ws too small for bf16 staging): fp32 LDS-tiled GEMM.
// ---------------------------------------------------------------------------
__global__ void gemm_fallback_kernel(const float* __restrict__ X, const float* __restrict__ Wt,
                                     const unsigned char* __restrict__ mraw,
                                     const int* __restrict__ flag, float* __restrict__ O) {
  __shared__ float sX[16][17];
  __shared__ float sW[16][17];
  const int tx = threadIdx.x & 15;
  const int ty = threadIdx.x >> 4;
  const long row = blockIdx.y * 16 + ty;
  const long colblock = blockIdx.x * 16;
  const int byteLayout = *flag;
  float acc = 0.f;
  for (int k0 = 0; k0 < Kdim; k0 += 16) {
    sX[ty][tx] = X[row * Kdim + k0 + tx];
    const long wi = (colblock + ty) * (long)Kdim + k0 + tx;
    const int mv = byteLayout ? (mraw[wi] != 0) : (((const int*)mraw)[wi] != 0);
    sW[ty][tx] = mv ? Wt[wi] : 0.f;
    __syncthreads();
#pragma unroll
    for (int k = 0; k < 16; ++k) acc += sX[ty][k] * sW[tx][k];
    __syncthreads();
  }
  O[row * Ndim + colblock + tx] = acc;
}

extern "C" void kernel_launch(void* const* d_in, const int* in_sizes, int n_in,
                              void* d_out, int out_size, void* d_ws, size_t ws_size,
                              hipStream_t stream) {
  const float* x = (const float*)d_in[0];               // [8192, 4096] fp32
  const float* w = (const float*)d_in[1];               // [4096, 4096] fp32
  const unsigned char* mask = (const unsigned char*)d_in[2];  // bool (layout detected)
  float* out = (float*)d_out;                           // [8192, 4096] fp32

  const size_t xb_off = 0;
  const size_t wb_off = (size_t)Mdim * Kdim * 2;             // 67,108,864
  const size_t flag_off = wb_off + (size_t)Ndim * Kdim * 2;  // 100,663,296
  const size_t needed = flag_off + 16;

  if (ws_size >= needed) {
    unsigned short* xb = (unsigned short*)((char*)d_ws + xb_off);
    unsigned short* wb = (unsigned short*)((char*)d_ws + wb_off);
    int* flag = (int*)((char*)d_ws + flag_off);

    hipMemsetAsync(flag, 0, sizeof(int), stream);
    detect_mask_kernel<<<64, 256, 0, stream>>>(mask, flag);
    cvt_x_kernel<<<(int)(((long)Mdim * Kdim / 8) / 256), 256, 0, stream>>>(x, xb);
    cvt_w_kernel<<<(int)(((long)Ndim * Kdim / 8) / 256), 256, 0, stream>>>(w, mask, flag, wb);
    gemm_bt_kernel<<<(Mdim / BM) * (Ndim / BN), 512, 0, stream>>>(xb, wb, out);
  } else {
    int* flag = (int*)d_ws;
    hipMemsetAsync(flag, 0, sizeof(int), stream);
    detect_mask_kernel<<<64, 256, 0, stream>>>(mask, flag);
    dim3 grid(Ndim / 16, Mdim / 16);
    gemm_fallback_kernel<<<grid, 256, 0, stream>>>(x, w, mask, flag, out);
  }
}